// Round 3
// baseline (2182.135 us; speedup 1.0000x reference)
//
#include <hip/hip_runtime.h>
#include <math.h>

#define BB 4
#define NN 512
#define DIMX 384
#define HH 8
#define DKK 16
#define DVV 16
#define PKK 4
#define PVV 8
#define PDD 64
#define JC 64

static constexpr float EPSV = 1e-8f;
static constexpr float SCALAR_SCALE = 0.14433756729740643f;  // (3*16)^-0.5
static constexpr float POINT_SCALE  = 0.1360827634879543f;   // (3*4*4.5)^-0.5
static constexpr float PAIR_SCALE   = 0.5773502691896258f;   // 3^-0.5

// ---------------- rope table ----------------
__global__ void k_rope(float* __restrict__ cos_t, float* __restrict__ sin_t) {
    int n = blockIdx.x * blockDim.x + threadIdx.x;
    if (n >= NN) return;
#pragma unroll
    for (int i = 0; i < 8; ++i) {
        float invf = powf(10000.0f, -(float)i / 8.0f);
        float f = (float)n * invf;
        cos_t[n * 8 + i] = cosf(f);
        sin_t[n * 8 + i] = sinf(f);
    }
}

// ---------------- projections + transforms ----------------
__global__ __launch_bounds__(256) void k_proj(
    const float* __restrict__ x, const float* __restrict__ rot,
    const float* __restrict__ trans, const int* __restrict__ pos_ids,
    const float* __restrict__ Wq_s, const float* __restrict__ Wk_s, const float* __restrict__ Wv_s,
    const float* __restrict__ Wq_p, const float* __restrict__ Wk_p, const float* __restrict__ Wv_p,
    const float* __restrict__ cos_t, const float* __restrict__ sin_t,
    float* __restrict__ qsg, float* __restrict__ ksg, float* __restrict__ vsg,
    float* __restrict__ qpg, float* __restrict__ kpg, float* __restrict__ vpg,
    float* __restrict__ qqg, float* __restrict__ kkg)
{
    __shared__ float xl[8][DIMX];
    __shared__ float raw[8][768];
    const int t = threadIdx.x;
    const int tok0 = blockIdx.x * 8;

    {
        const float4* xg = (const float4*)(x + (size_t)tok0 * DIMX);
        float4* xl4 = (float4*)&xl[0][0];
#pragma unroll
        for (int k = 0; k < 3; ++k) xl4[t + 256 * k] = xg[t + 256 * k];
    }
    __syncthreads();

    const int tok = t >> 5, l = t & 31;
    {
        float4 acc[6];
        const float* wb[6];
        int st[6];
#pragma unroll
        for (int m = 0; m < 6; ++m) {
            int f = l + 32 * m;
            const float* w; int out, c;
            if (f < 32)       { w = Wq_s; out = 128; c = 4 * f; }
            else if (f < 64)  { w = Wk_s; out = 128; c = 4 * f - 128; }
            else if (f < 96)  { w = Wv_s; out = 128; c = 4 * f - 256; }
            else if (f < 120) { w = Wq_p; out = 96;  c = 4 * f - 384; }
            else if (f < 144) { w = Wk_p; out = 96;  c = 4 * f - 480; }
            else              { w = Wv_p; out = 192; c = 4 * f - 576; }
            wb[m] = w + c; st[m] = out;
            acc[m] = make_float4(0.f, 0.f, 0.f, 0.f);
        }
        for (int dd = 0; dd < DIMX; ++dd) {
            float xv = xl[tok][dd];
#pragma unroll
            for (int m = 0; m < 6; ++m) {
                float4 wv = *(const float4*)(wb[m] + (size_t)dd * st[m]);
                acc[m].x = fmaf(xv, wv.x, acc[m].x);
                acc[m].y = fmaf(xv, wv.y, acc[m].y);
                acc[m].z = fmaf(xv, wv.z, acc[m].z);
                acc[m].w = fmaf(xv, wv.w, acc[m].w);
            }
        }
#pragma unroll
        for (int m = 0; m < 6; ++m) {
            int f = l + 32 * m;
            *(float4*)&raw[tok][4 * f] = acc[m];
        }
    }
    __syncthreads();

    const int h = l >> 2, q = l & 3;
    const int n_g = tok0 + tok;
    const int b = n_g / NN;
    const int pos = pos_ids[n_g];
    const float* Rm = rot + (size_t)n_g * 9;
    const float tr0 = trans[n_g * 3 + 0], tr1 = trans[n_g * 3 + 1], tr2 = trans[n_g * 3 + 2];
    const size_t rowi = ((size_t)(b * HH + h)) * NN + (n_g - b * NN);

#pragma unroll
    for (int dd0 = 0; dd0 < 4; ++dd0) {
        int dd = q * 4 + dd0;
        int i8 = dd & 7;
        float c = cos_t[pos * 8 + i8], s = sin_t[pos * 8 + i8];
        float xq = raw[tok][h * 16 + dd];
        float rq = (dd < 8) ? -raw[tok][h * 16 + dd + 8] : raw[tok][h * 16 + dd - 8];
        qsg[rowi * DKK + dd] = fmaf(xq, c, rq * s);
        float xk = raw[tok][128 + h * 16 + dd];
        float rk = (dd < 8) ? -raw[tok][128 + h * 16 + dd + 8] : raw[tok][128 + h * 16 + dd - 8];
        ksg[rowi * DKK + dd] = fmaf(xk, c, rk * s);
        vsg[rowi * DVV + dd] = raw[tok][256 + h * 16 + dd];
    }

    float qqp = 0.f, kkp = 0.f;
    {
        const int p = q;
        float pc[3], kc[3];
#pragma unroll
        for (int c = 0; c < 3; ++c) {
            pc[c] = raw[tok][384 + h * 12 + p * 3 + c];
            kc[c] = raw[tok][480 + h * 12 + p * 3 + c];
        }
        const float trv[3] = {tr0, tr1, tr2};
#pragma unroll
        for (int r = 0; r < 3; ++r) {
            float vq = trv[r], vk = trv[r];
#pragma unroll
            for (int c = 0; c < 3; ++c) {
                vq = fmaf(pc[c], Rm[c * 3 + r], vq);
                vk = fmaf(kc[c], Rm[c * 3 + r], vk);
            }
            qpg[rowi * 12 + p * 3 + r] = vq;
            kpg[rowi * 12 + p * 3 + r] = vk;
            qqp = fmaf(vq, vq, qqp);
            kkp = fmaf(vk, vk, kkp);
        }
    }
    qqp += __shfl_xor(qqp, 1); qqp += __shfl_xor(qqp, 2);
    kkp += __shfl_xor(kkp, 1); kkp += __shfl_xor(kkp, 2);
    if (q == 0) { qqg[rowi] = qqp; kkg[rowi] = kkp; }

    {
        const float trv[3] = {tr0, tr1, tr2};
#pragma unroll
        for (int pp = 0; pp < 2; ++pp) {
            int p = q + 4 * pp;
            float pc[3];
#pragma unroll
            for (int c = 0; c < 3; ++c) pc[c] = raw[tok][576 + h * 24 + p * 3 + c];
#pragma unroll
            for (int r = 0; r < 3; ++r) {
                float v = trv[r];
#pragma unroll
                for (int c = 0; c < 3; ++c) v = fmaf(pc[c], Rm[c * 3 + r], v);
                vpg[rowi * 24 + p * 3 + r] = v;
            }
        }
    }
}

// ---------------- fused attention: 512 threads, wave = head, lane = j ----------------
__global__ __launch_bounds__(512, 4) void k_attn(
    const float* __restrict__ pairw,
    const float* __restrict__ rot, const float* __restrict__ trans,
    const float* __restrict__ Wpair, const float* __restrict__ bpair,
    const float* __restrict__ pweights,
    const float* __restrict__ qsg, const float* __restrict__ ksg, const float* __restrict__ vsg,
    const float* __restrict__ qpg, const float* __restrict__ kpg, const float* __restrict__ vpg,
    const float* __restrict__ qqg, const float* __restrict__ kkg,
    float* __restrict__ feats)
{
    __shared__ float pw[2][JC][65];    // double-buffered pairwise tile (+1 pad)
    __shared__ float Wp_t[HH][64];     // W_pair transposed [h][d]
    __shared__ float plds[HH][JC];     // per-head probs (same-wave write->read)

    const int t = threadIdx.x;
    const int bi = blockIdx.x;
    const int b = bi >> 9;
    const int h = t >> 6, l = t & 63;  // wave = head, lane = j-in-chunk

    { int d = t >> 3, hh = t & 7; Wp_t[hh][d] = Wpair[t]; }

    const size_t bhN = ((size_t)(b * HH + h)) * NN;
    const size_t rowq = bhN + (bi & 511);

    // q in registers (lane-uniform values)
    float qs_r[16], qp_r[12];
    {
        const float4* q4 = (const float4*)(qsg + rowq * 16);
#pragma unroll
        for (int k = 0; k < 4; ++k) {
            float4 v = q4[k];
            qs_r[4 * k] = v.x; qs_r[4 * k + 1] = v.y; qs_r[4 * k + 2] = v.z; qs_r[4 * k + 3] = v.w;
        }
        const float4* p4 = (const float4*)(qpg + rowq * 12);
#pragma unroll
        for (int k = 0; k < 3; ++k) {
            float4 v = p4[k];
            qp_r[4 * k] = v.x; qp_r[4 * k + 1] = v.y; qp_r[4 * k + 2] = v.z; qp_r[4 * k + 3] = v.w;
        }
    }
    const float qq_r = qqg[rowq];
    const float coefP = -0.5f * log1pf(__expf(pweights[h])) * POINT_SCALE;
    const float bp_h = bpair[h];

    const float* pwrow = pairw + (size_t)bi * NN * PDD;
    // prologue: stage chunk 0
    {
        const float4* src = (const float4*)pwrow;
        float4 sA = src[t], sB = src[t + 512];
        int jA = t >> 4, dA = (t & 15) * 4;
        *(float4*)&pw[0][jA][dA] = sA;
        int f2 = t + 512;
        *(float4*)&pw[0][f2 >> 4][(f2 & 15) * 4] = sB;
    }
    __syncthreads();

    float m = -3.0e38f, lsum = 0.f, ap = 0.f;
    float ascd[16], aptd[24];
#pragma unroll
    for (int d = 0; d < 16; ++d) ascd[d] = 0.f;
#pragma unroll
    for (int d = 0; d < 24; ++d) aptd[d] = 0.f;

    for (int c = 0; c < NN / JC; ++c) {
        const int cur = c & 1, nxt = cur ^ 1;
        // issue next-chunk loads early (latency hides under compute)
        float4 nA, nB;
        if (c < NN / JC - 1) {
            const float4* srcn = (const float4*)(pwrow + (size_t)(c + 1) * JC * PDD);
            nA = srcn[t]; nB = srcn[t + 512];
        }
        // ---- pair bias for my j (wave-local, no barrier) ----
        float bias = 0.f;
#pragma unroll
        for (int d4 = 0; d4 < 16; ++d4) {
            float4 pv = *(const float4*)&pw[cur][l][d4 * 4];
            float4 wv = *(const float4*)&Wp_t[h][d4 * 4];
            bias = fmaf(pv.x, wv.x, bias); bias = fmaf(pv.y, wv.y, bias);
            bias = fmaf(pv.z, wv.z, bias); bias = fmaf(pv.w, wv.w, bias);
        }
        bias = (bias + bp_h) * PAIR_SCALE;
        // ---- logit ----
        const size_t jrow = bhN + c * JC + l;
        float lg;
        {
            const float4* kr = (const float4*)(ksg + jrow * 16);
            float4 k0 = kr[0], k1 = kr[1], k2 = kr[2], k3 = kr[3];
            float dot = 0.f;
            dot = fmaf(qs_r[0], k0.x, dot);  dot = fmaf(qs_r[1], k0.y, dot);
            dot = fmaf(qs_r[2], k0.z, dot);  dot = fmaf(qs_r[3], k0.w, dot);
            dot = fmaf(qs_r[4], k1.x, dot);  dot = fmaf(qs_r[5], k1.y, dot);
            dot = fmaf(qs_r[6], k1.z, dot);  dot = fmaf(qs_r[7], k1.w, dot);
            dot = fmaf(qs_r[8], k2.x, dot);  dot = fmaf(qs_r[9], k2.y, dot);
            dot = fmaf(qs_r[10], k2.z, dot); dot = fmaf(qs_r[11], k2.w, dot);
            dot = fmaf(qs_r[12], k3.x, dot); dot = fmaf(qs_r[13], k3.y, dot);
            dot = fmaf(qs_r[14], k3.z, dot); dot = fmaf(qs_r[15], k3.w, dot);
            const float4* kp = (const float4*)(kpg + jrow * 12);
            float4 p0 = kp[0], p1 = kp[1], p2 = kp[2];
            float pdot = 0.f;
            pdot = fmaf(qp_r[0], p0.x, pdot);  pdot = fmaf(qp_r[1], p0.y, pdot);
            pdot = fmaf(qp_r[2], p0.z, pdot);  pdot = fmaf(qp_r[3], p0.w, pdot);
            pdot = fmaf(qp_r[4], p1.x, pdot);  pdot = fmaf(qp_r[5], p1.y, pdot);
            pdot = fmaf(qp_r[6], p1.z, pdot);  pdot = fmaf(qp_r[7], p1.w, pdot);
            pdot = fmaf(qp_r[8], p2.x, pdot);  pdot = fmaf(qp_r[9], p2.y, pdot);
            pdot = fmaf(qp_r[10], p2.z, pdot); pdot = fmaf(qp_r[11], p2.w, pdot);
            float dist = qq_r + kkg[jrow] - 2.f * pdot;
            lg = fmaf(dot, SCALAR_SCALE, fmaf(coefP, dist, bias));
        }
        // ---- online softmax across the 64-lane wave ----
        float cmax = lg;
#pragma unroll
        for (int off = 32; off > 0; off >>= 1) cmax = fmaxf(cmax, __shfl_xor(cmax, off));
        const float mnew = fmaxf(m, cmax);
        const float scale = __expf(m - mnew);
        const float p = __expf(lg - mnew);
        float psum = p;
#pragma unroll
        for (int off = 32; off > 0; off >>= 1) psum += __shfl_xor(psum, off);
        m = mnew;
        lsum = fmaf(lsum, scale, psum);
        plds[h][l] = p;
        // ---- rescale accumulators ----
#pragma unroll
        for (int d = 0; d < 16; ++d) ascd[d] *= scale;
#pragma unroll
        for (int d = 0; d < 24; ++d) aptd[d] *= scale;
        ap *= scale;
        // ---- v accumulation (lane owns j, coalesced rows) ----
        {
            const float4* vr = (const float4*)(vsg + jrow * 16);
            float4 a0 = vr[0], a1 = vr[1], a2 = vr[2], a3 = vr[3];
            ascd[0]  = fmaf(p, a0.x, ascd[0]);  ascd[1]  = fmaf(p, a0.y, ascd[1]);
            ascd[2]  = fmaf(p, a0.z, ascd[2]);  ascd[3]  = fmaf(p, a0.w, ascd[3]);
            ascd[4]  = fmaf(p, a1.x, ascd[4]);  ascd[5]  = fmaf(p, a1.y, ascd[5]);
            ascd[6]  = fmaf(p, a1.z, ascd[6]);  ascd[7]  = fmaf(p, a1.w, ascd[7]);
            ascd[8]  = fmaf(p, a2.x, ascd[8]);  ascd[9]  = fmaf(p, a2.y, ascd[9]);
            ascd[10] = fmaf(p, a2.z, ascd[10]); ascd[11] = fmaf(p, a2.w, ascd[11]);
            ascd[12] = fmaf(p, a3.x, ascd[12]); ascd[13] = fmaf(p, a3.y, ascd[13]);
            ascd[14] = fmaf(p, a3.z, ascd[14]); ascd[15] = fmaf(p, a3.w, ascd[15]);
            const float4* vp = (const float4*)(vpg + jrow * 24);
            float4 b0 = vp[0], b1 = vp[1], b2 = vp[2], b3 = vp[3], b4 = vp[4], b5 = vp[5];
            aptd[0]  = fmaf(p, b0.x, aptd[0]);  aptd[1]  = fmaf(p, b0.y, aptd[1]);
            aptd[2]  = fmaf(p, b0.z, aptd[2]);  aptd[3]  = fmaf(p, b0.w, aptd[3]);
            aptd[4]  = fmaf(p, b1.x, aptd[4]);  aptd[5]  = fmaf(p, b1.y, aptd[5]);
            aptd[6]  = fmaf(p, b1.z, aptd[6]);  aptd[7]  = fmaf(p, b1.w, aptd[7]);
            aptd[8]  = fmaf(p, b2.x, aptd[8]);  aptd[9]  = fmaf(p, b2.y, aptd[9]);
            aptd[10] = fmaf(p, b2.z, aptd[10]); aptd[11] = fmaf(p, b2.w, aptd[11]);
            aptd[12] = fmaf(p, b3.x, aptd[12]); aptd[13] = fmaf(p, b3.y, aptd[13]);
            aptd[14] = fmaf(p, b3.z, aptd[14]); aptd[15] = fmaf(p, b3.w, aptd[15]);
            aptd[16] = fmaf(p, b4.x, aptd[16]); aptd[17] = fmaf(p, b4.y, aptd[17]);
            aptd[18] = fmaf(p, b4.z, aptd[18]); aptd[19] = fmaf(p, b4.w, aptd[19]);
            aptd[20] = fmaf(p, b5.x, aptd[20]); aptd[21] = fmaf(p, b5.y, aptd[21]);
            aptd[22] = fmaf(p, b5.z, aptd[22]); aptd[23] = fmaf(p, b5.w, aptd[23]);
        }
        // ---- pair accumulation: lane owns output dim d = l ----
#pragma unroll
        for (int u = 0; u < JC / 4; ++u) {
            float4 p4 = *(const float4*)&plds[h][4 * u];
            ap = fmaf(p4.x, pw[cur][4 * u + 0][l], ap);
            ap = fmaf(p4.y, pw[cur][4 * u + 1][l], ap);
            ap = fmaf(p4.z, pw[cur][4 * u + 2][l], ap);
            ap = fmaf(p4.w, pw[cur][4 * u + 3][l], ap);
        }
        // ---- write next chunk to other buffer ----
        if (c < NN / JC - 1) {
            int jA = t >> 4, dA = (t & 15) * 4;
            *(float4*)&pw[nxt][jA][dA] = nA;
            int f2 = t + 512;
            *(float4*)&pw[nxt][f2 >> 4][(f2 & 15) * 4] = nB;
        }
        __syncthreads();
    }

    // ---- epilogue: butterfly-reduce j-partials across 64 lanes ----
#pragma unroll
    for (int off = 32; off > 0; off >>= 1) {
#pragma unroll
        for (int d = 0; d < 16; ++d) ascd[d] += __shfl_xor(ascd[d], off);
#pragma unroll
        for (int d = 0; d < 24; ++d) aptd[d] += __shfl_xor(aptd[d], off);
    }
    const float inv_l = 1.f / lsum;
    float* fb = feats + (size_t)bi * 896;
    if (l < 16) fb[h * 16 + l] = ascd[l] * inv_l;             // m_scalar
    fb[384 + h * 64 + l] = ap * inv_l;                        // m_pair (lane owns d=l)
    const float tr0 = trans[bi * 3 + 0], tr1 = trans[bi * 3 + 1], tr2 = trans[bi * 3 + 2];
    if (l < 24) {
        const int pp = l / 3, r = l - pp * 3;
        const float c0 = aptd[pp * 3 + 0] * inv_l - tr0;
        const float c1 = aptd[pp * 3 + 1] * inv_l - tr1;
        const float c2 = aptd[pp * 3 + 2] * inv_l - tr2;
        const float* Rm = rot + (size_t)bi * 9 + r * 3;       // R[r][c]
        fb[128 + h * 24 + pp * 3 + r] = fmaf(c0, Rm[0], fmaf(c1, Rm[1], c2 * Rm[2]));
    }
    if (l < 8) {
        const float c0 = aptd[l * 3 + 0] * inv_l - tr0;
        const float c1 = aptd[l * 3 + 1] * inv_l - tr1;
        const float c2 = aptd[l * 3 + 2] * inv_l - tr2;
        fb[320 + h * 8 + l] = sqrtf(fmaf(c0, c0, fmaf(c1, c1, fmaf(c2, c2, EPSV))));
    }
}

// ---------------- output projection ----------------
__global__ __launch_bounds__(256) void k_out(
    const float* __restrict__ feats, const float* __restrict__ Wout,
    const float* __restrict__ bout, float* __restrict__ out)
{
    __shared__ float fl[8][896];
    const int t = threadIdx.x;
    const int tok0 = blockIdx.x * 8;
    {
        const float4* src = (const float4*)(feats + (size_t)tok0 * 896);
        float4* dst = (float4*)&fl[0][0];
#pragma unroll
        for (int k = 0; k < 7; ++k) dst[t + 256 * k] = src[t + 256 * k];
    }
    __syncthreads();
    const int tok = t >> 5, l = t & 31;
    float4 acc[3];
#pragma unroll
    for (int m = 0; m < 3; ++m) acc[m] = make_float4(0.f, 0.f, 0.f, 0.f);
    for (int dd = 0; dd < 896; ++dd) {
        float fv = fl[tok][dd];
        const float* wr = Wout + (size_t)dd * 384;
#pragma unroll
        for (int m = 0; m < 3; ++m) {
            float4 wv = *(const float4*)(wr + 4 * (l + 32 * m));
            acc[m].x = fmaf(fv, wv.x, acc[m].x);
            acc[m].y = fmaf(fv, wv.y, acc[m].y);
            acc[m].z = fmaf(fv, wv.z, acc[m].z);
            acc[m].w = fmaf(fv, wv.w, acc[m].w);
        }
    }
    float* ob = out + (size_t)(tok0 + tok) * 384;
#pragma unroll
    for (int m = 0; m < 3; ++m) {
        int c = 4 * (l + 32 * m);
        float4 bv = *(const float4*)(bout + c);
        float4 r = make_float4(acc[m].x + bv.x, acc[m].y + bv.y, acc[m].z + bv.z, acc[m].w + bv.w);
        *(float4*)(ob + c) = r;
    }
}

extern "C" void kernel_launch(void* const* d_in, const int* in_sizes, int n_in,
                              void* d_out, int out_size, void* d_ws, size_t ws_size,
                              hipStream_t stream) {
    const float* x        = (const float*)d_in[0];
    const float* pairw    = (const float*)d_in[1];
    const float* rot      = (const float*)d_in[2];
    const float* trans    = (const float*)d_in[3];
    const int*   pos      = (const int*)d_in[4];
    const float* Wq_s     = (const float*)d_in[6];
    const float* Wk_s     = (const float*)d_in[7];
    const float* Wv_s     = (const float*)d_in[8];
    const float* Wq_p     = (const float*)d_in[9];
    const float* Wk_p     = (const float*)d_in[10];
    const float* Wv_p     = (const float*)d_in[11];
    const float* pweights = (const float*)d_in[12];
    const float* Wpair    = (const float*)d_in[13];
    const float* bpair    = (const float*)d_in[14];
    const float* Wout     = (const float*)d_in[15];
    const float* bout     = (const float*)d_in[16];
    float* out = (float*)d_out;

    float* ws = (float*)d_ws;
    float* cos_t = ws;  ws += 4096;
    float* sin_t = ws;  ws += 4096;
    float* qsg = ws;    ws += BB * HH * NN * DKK;
    float* ksg = ws;    ws += BB * HH * NN * DKK;
    float* vsg = ws;    ws += BB * HH * NN * DVV;
    float* qpg = ws;    ws += BB * HH * NN * 12;
    float* kpg = ws;    ws += BB * HH * NN * 12;
    float* vpg = ws;    ws += BB * HH * NN * 24;
    float* qqg = ws;    ws += BB * HH * NN;
    float* kkg = ws;    ws += BB * HH * NN;
    float* feats = ws;  ws += BB * NN * 896;

    k_rope<<<2, 256, 0, stream>>>(cos_t, sin_t);
    k_proj<<<(BB * NN) / 8, 256, 0, stream>>>(x, rot, trans, pos,
        Wq_s, Wk_s, Wv_s, Wq_p, Wk_p, Wv_p, cos_t, sin_t,
        qsg, ksg, vsg, qpg, kpg, vpg, qqg, kkg);
    k_attn<<<BB * NN, 512, 0, stream>>>(pairw, rot, trans, Wpair, bpair, pweights,
        qsg, ksg, vsg, qpg, kpg, vpg, qqg, kkg, feats);
    k_out<<<(BB * NN) / 8, 256, 0, stream>>>(feats, Wout, bout, out);

    (void)in_sizes; (void)n_in; (void)out_size; (void)ws_size;
}

// Round 4
// 623.951 us; speedup vs baseline: 3.4973x; 3.4973x over previous
//
#include <hip/hip_runtime.h>
#include <math.h>

#define BB 4
#define NN 512
#define DIMX 384
#define HH 8
#define DKK 16
#define DVV 16
#define PKK 4
#define PVV 8
#define PDD 64
#define JC 64

static constexpr float EPSV = 1e-8f;
static constexpr float SCALAR_SCALE = 0.14433756729740643f;  // (3*16)^-0.5
static constexpr float POINT_SCALE  = 0.1360827634879543f;   // (3*4*4.5)^-0.5
static constexpr float PAIR_SCALE   = 0.5773502691896258f;   // 3^-0.5

// ---------------- rope table ----------------
__global__ void k_rope(float* __restrict__ cos_t, float* __restrict__ sin_t) {
    int n = blockIdx.x * blockDim.x + threadIdx.x;
    if (n >= NN) return;
#pragma unroll
    for (int i = 0; i < 8; ++i) {
        float invf = powf(10000.0f, -(float)i / 8.0f);
        float f = (float)n * invf;
        cos_t[n * 8 + i] = cosf(f);
        sin_t[n * 8 + i] = sinf(f);
    }
}

// ---------------- projections + transforms ----------------
__global__ __launch_bounds__(256) void k_proj(
    const float* __restrict__ x, const float* __restrict__ rot,
    const float* __restrict__ trans, const int* __restrict__ pos_ids,
    const float* __restrict__ Wq_s, const float* __restrict__ Wk_s, const float* __restrict__ Wv_s,
    const float* __restrict__ Wq_p, const float* __restrict__ Wk_p, const float* __restrict__ Wv_p,
    const float* __restrict__ cos_t, const float* __restrict__ sin_t,
    float* __restrict__ qsg, float* __restrict__ ksg, float* __restrict__ vsg,
    float* __restrict__ qpg, float* __restrict__ kpg, float* __restrict__ vpg,
    float* __restrict__ qqg, float* __restrict__ kkg)
{
    __shared__ float xl[8][DIMX];
    __shared__ float raw[8][768];
    const int t = threadIdx.x;
    const int tok0 = blockIdx.x * 8;

    {
        const float4* xg = (const float4*)(x + (size_t)tok0 * DIMX);
        float4* xl4 = (float4*)&xl[0][0];
#pragma unroll
        for (int k = 0; k < 3; ++k) xl4[t + 256 * k] = xg[t + 256 * k];
    }
    __syncthreads();

    const int tok = t >> 5, l = t & 31;
    {
        float4 acc[6];
        const float* wb[6];
        int st[6];
#pragma unroll
        for (int m = 0; m < 6; ++m) {
            int f = l + 32 * m;
            const float* w; int out, c;
            if (f < 32)       { w = Wq_s; out = 128; c = 4 * f; }
            else if (f < 64)  { w = Wk_s; out = 128; c = 4 * f - 128; }
            else if (f < 96)  { w = Wv_s; out = 128; c = 4 * f - 256; }
            else if (f < 120) { w = Wq_p; out = 96;  c = 4 * f - 384; }
            else if (f < 144) { w = Wk_p; out = 96;  c = 4 * f - 480; }
            else              { w = Wv_p; out = 192; c = 4 * f - 576; }
            wb[m] = w + c; st[m] = out;
            acc[m] = make_float4(0.f, 0.f, 0.f, 0.f);
        }
        for (int dd = 0; dd < DIMX; ++dd) {
            float xv = xl[tok][dd];
#pragma unroll
            for (int m = 0; m < 6; ++m) {
                float4 wv = *(const float4*)(wb[m] + (size_t)dd * st[m]);
                acc[m].x = fmaf(xv, wv.x, acc[m].x);
                acc[m].y = fmaf(xv, wv.y, acc[m].y);
                acc[m].z = fmaf(xv, wv.z, acc[m].z);
                acc[m].w = fmaf(xv, wv.w, acc[m].w);
            }
        }
#pragma unroll
        for (int m = 0; m < 6; ++m) {
            int f = l + 32 * m;
            *(float4*)&raw[tok][4 * f] = acc[m];
        }
    }
    __syncthreads();

    const int h = l >> 2, q = l & 3;
    const int n_g = tok0 + tok;
    const int b = n_g / NN;
    const int pos = pos_ids[n_g];
    const float* Rm = rot + (size_t)n_g * 9;
    const float tr0 = trans[n_g * 3 + 0], tr1 = trans[n_g * 3 + 1], tr2 = trans[n_g * 3 + 2];
    const size_t rowi = ((size_t)(b * HH + h)) * NN + (n_g - b * NN);

#pragma unroll
    for (int dd0 = 0; dd0 < 4; ++dd0) {
        int dd = q * 4 + dd0;
        int i8 = dd & 7;
        float c = cos_t[pos * 8 + i8], s = sin_t[pos * 8 + i8];
        float xq = raw[tok][h * 16 + dd];
        float rq = (dd < 8) ? -raw[tok][h * 16 + dd + 8] : raw[tok][h * 16 + dd - 8];
        qsg[rowi * DKK + dd] = fmaf(xq, c, rq * s);
        float xk = raw[tok][128 + h * 16 + dd];
        float rk = (dd < 8) ? -raw[tok][128 + h * 16 + dd + 8] : raw[tok][128 + h * 16 + dd - 8];
        ksg[rowi * DKK + dd] = fmaf(xk, c, rk * s);
        vsg[rowi * DVV + dd] = raw[tok][256 + h * 16 + dd];
    }

    float qqp = 0.f, kkp = 0.f;
    {
        const int p = q;
        float pc[3], kc[3];
#pragma unroll
        for (int c = 0; c < 3; ++c) {
            pc[c] = raw[tok][384 + h * 12 + p * 3 + c];
            kc[c] = raw[tok][480 + h * 12 + p * 3 + c];
        }
        const float trv[3] = {tr0, tr1, tr2};
#pragma unroll
        for (int r = 0; r < 3; ++r) {
            float vq = trv[r], vk = trv[r];
#pragma unroll
            for (int c = 0; c < 3; ++c) {
                vq = fmaf(pc[c], Rm[c * 3 + r], vq);
                vk = fmaf(kc[c], Rm[c * 3 + r], vk);
            }
            qpg[rowi * 12 + p * 3 + r] = vq;
            kpg[rowi * 12 + p * 3 + r] = vk;
            qqp = fmaf(vq, vq, qqp);
            kkp = fmaf(vk, vk, kkp);
        }
    }
    qqp += __shfl_xor(qqp, 1); qqp += __shfl_xor(qqp, 2);
    kkp += __shfl_xor(kkp, 1); kkp += __shfl_xor(kkp, 2);
    if (q == 0) { qqg[rowi] = qqp; kkg[rowi] = kkp; }

    {
        const float trv[3] = {tr0, tr1, tr2};
#pragma unroll
        for (int pp = 0; pp < 2; ++pp) {
            int p = q + 4 * pp;
            float pc[3];
#pragma unroll
            for (int c = 0; c < 3; ++c) pc[c] = raw[tok][576 + h * 24 + p * 3 + c];
#pragma unroll
            for (int r = 0; r < 3; ++r) {
                float v = trv[r];
#pragma unroll
                for (int c = 0; c < 3; ++c) v = fmaf(pc[c], Rm[c * 3 + r], v);
                vpg[rowi * 24 + p * 3 + r] = v;
            }
        }
    }
}

// ---------------- fused attention: 512 threads, wave = head, lane = j ----------------
// Bare launch bounds: the (512,4)/(256,4) occupancy hints squeezed VGPR to 64
// and spilled ~40 regs -> 7 GB scratch traffic (round 3). ~100 live regs here.
__global__ __launch_bounds__(512) void k_attn(
    const float* __restrict__ pairw,
    const float* __restrict__ rot, const float* __restrict__ trans,
    const float* __restrict__ Wpair, const float* __restrict__ bpair,
    const float* __restrict__ pweights,
    const float* __restrict__ qsg, const float* __restrict__ ksg, const float* __restrict__ vsg,
    const float* __restrict__ qpg, const float* __restrict__ kpg, const float* __restrict__ vpg,
    const float* __restrict__ qqg, const float* __restrict__ kkg,
    float* __restrict__ feats)
{
    __shared__ float pw[JC][65];       // single-buffer pairwise tile, pad 65: scalar access conflict-free
    __shared__ float Wp_t[HH][64];     // W_pair transposed [h][d]
    __shared__ float plds[HH][JC];     // per-head probs (same-wave write->read)

    const int t = threadIdx.x;
    const int bi = blockIdx.x;
    const int b = bi >> 9;
    const int h = t >> 6, l = t & 63;  // wave = head, lane = j-in-chunk

    { int d = t >> 3, hh = t & 7; Wp_t[hh][d] = Wpair[t]; }

    const size_t bhN = ((size_t)(b * HH + h)) * NN;
    const size_t rowq = bhN + (bi & 511);

    // q in registers (lane-uniform values)
    float qs_r[16], qp_r[12];
    {
        const float4* q4 = (const float4*)(qsg + rowq * 16);
#pragma unroll
        for (int k = 0; k < 4; ++k) {
            float4 v = q4[k];
            qs_r[4 * k] = v.x; qs_r[4 * k + 1] = v.y; qs_r[4 * k + 2] = v.z; qs_r[4 * k + 3] = v.w;
        }
        const float4* p4 = (const float4*)(qpg + rowq * 12);
#pragma unroll
        for (int k = 0; k < 3; ++k) {
            float4 v = p4[k];
            qp_r[4 * k] = v.x; qp_r[4 * k + 1] = v.y; qp_r[4 * k + 2] = v.z; qp_r[4 * k + 3] = v.w;
        }
    }
    const float qq_r = qqg[rowq];
    const float coefP = -0.5f * log1pf(__expf(pweights[h])) * POINT_SCALE;
    const float bp_h = bpair[h];

    const float* pwrow = pairw + (size_t)bi * NN * PDD;

    float m = -3.0e38f, lsum = 0.f, ap = 0.f;
    float ascd[16], aptd[24];
#pragma unroll
    for (int d = 0; d < 16; ++d) ascd[d] = 0.f;
#pragma unroll
    for (int d = 0; d < 24; ++d) aptd[d] = 0.f;

    for (int c = 0; c < NN / JC; ++c) {
        __syncthreads();   // everyone done reading pw from previous chunk
        // stage pairwise tile (64 x 64), scalar LDS writes (pad-65 safe, ~2-way banks)
        {
            const float4* src = (const float4*)(pwrow + (size_t)c * JC * PDD);
            float4 vA = src[t];
            int jA = t >> 4, dA = (t & 15) * 4;
            pw[jA][dA] = vA.x; pw[jA][dA + 1] = vA.y; pw[jA][dA + 2] = vA.z; pw[jA][dA + 3] = vA.w;
            float4 vB = src[t + 512];
            int f2 = t + 512;
            int jB = f2 >> 4, dB = (f2 & 15) * 4;
            pw[jB][dB] = vB.x; pw[jB][dB + 1] = vB.y; pw[jB][dB + 2] = vB.z; pw[jB][dB + 3] = vB.w;
        }
        __syncthreads();
        // ---- pair bias for my j (wave-local, conflict-free: bank (l+d)%32) ----
        float bias = 0.f;
#pragma unroll
        for (int d = 0; d < 64; ++d)
            bias = fmaf(pw[l][d], Wp_t[h][d], bias);
        bias = (bias + bp_h) * PAIR_SCALE;
        // ---- logit ----
        const size_t jrow = bhN + c * JC + l;
        float lg;
        {
            const float4* kr = (const float4*)(ksg + jrow * 16);
            float4 k0 = kr[0], k1 = kr[1], k2 = kr[2], k3 = kr[3];
            float dot = 0.f;
            dot = fmaf(qs_r[0], k0.x, dot);  dot = fmaf(qs_r[1], k0.y, dot);
            dot = fmaf(qs_r[2], k0.z, dot);  dot = fmaf(qs_r[3], k0.w, dot);
            dot = fmaf(qs_r[4], k1.x, dot);  dot = fmaf(qs_r[5], k1.y, dot);
            dot = fmaf(qs_r[6], k1.z, dot);  dot = fmaf(qs_r[7], k1.w, dot);
            dot = fmaf(qs_r[8], k2.x, dot);  dot = fmaf(qs_r[9], k2.y, dot);
            dot = fmaf(qs_r[10], k2.z, dot); dot = fmaf(qs_r[11], k2.w, dot);
            dot = fmaf(qs_r[12], k3.x, dot); dot = fmaf(qs_r[13], k3.y, dot);
            dot = fmaf(qs_r[14], k3.z, dot); dot = fmaf(qs_r[15], k3.w, dot);
            const float4* kp = (const float4*)(kpg + jrow * 12);
            float4 p0 = kp[0], p1 = kp[1], p2 = kp[2];
            float pdot = 0.f;
            pdot = fmaf(qp_r[0], p0.x, pdot);  pdot = fmaf(qp_r[1], p0.y, pdot);
            pdot = fmaf(qp_r[2], p0.z, pdot);  pdot = fmaf(qp_r[3], p0.w, pdot);
            pdot = fmaf(qp_r[4], p1.x, pdot);  pdot = fmaf(qp_r[5], p1.y, pdot);
            pdot = fmaf(qp_r[6], p1.z, pdot);  pdot = fmaf(qp_r[7], p1.w, pdot);
            pdot = fmaf(qp_r[8], p2.x, pdot);  pdot = fmaf(qp_r[9], p2.y, pdot);
            pdot = fmaf(qp_r[10], p2.z, pdot); pdot = fmaf(qp_r[11], p2.w, pdot);
            float dist = qq_r + kkg[jrow] - 2.f * pdot;
            lg = fmaf(dot, SCALAR_SCALE, fmaf(coefP, dist, bias));
        }
        // ---- online softmax across the 64-lane wave ----
        float cmax = lg;
#pragma unroll
        for (int off = 32; off > 0; off >>= 1) cmax = fmaxf(cmax, __shfl_xor(cmax, off));
        const float mnew = fmaxf(m, cmax);
        const float scale = __expf(m - mnew);
        const float p = __expf(lg - mnew);
        float psum = p;
#pragma unroll
        for (int off = 32; off > 0; off >>= 1) psum += __shfl_xor(psum, off);
        m = mnew;
        lsum = fmaf(lsum, scale, psum);
        plds[h][l] = p;
        // ---- rescale accumulators ----
#pragma unroll
        for (int d = 0; d < 16; ++d) ascd[d] *= scale;
#pragma unroll
        for (int d = 0; d < 24; ++d) aptd[d] *= scale;
        ap *= scale;
        // ---- v accumulation (lane owns j, coalesced rows) ----
        {
            const float4* vr = (const float4*)(vsg + jrow * 16);
            float4 a0 = vr[0], a1 = vr[1], a2 = vr[2], a3 = vr[3];
            ascd[0]  = fmaf(p, a0.x, ascd[0]);  ascd[1]  = fmaf(p, a0.y, ascd[1]);
            ascd[2]  = fmaf(p, a0.z, ascd[2]);  ascd[3]  = fmaf(p, a0.w, ascd[3]);
            ascd[4]  = fmaf(p, a1.x, ascd[4]);  ascd[5]  = fmaf(p, a1.y, ascd[5]);
            ascd[6]  = fmaf(p, a1.z, ascd[6]);  ascd[7]  = fmaf(p, a1.w, ascd[7]);
            ascd[8]  = fmaf(p, a2.x, ascd[8]);  ascd[9]  = fmaf(p, a2.y, ascd[9]);
            ascd[10] = fmaf(p, a2.z, ascd[10]); ascd[11] = fmaf(p, a2.w, ascd[11]);
            ascd[12] = fmaf(p, a3.x, ascd[12]); ascd[13] = fmaf(p, a3.y, ascd[13]);
            ascd[14] = fmaf(p, a3.z, ascd[14]); ascd[15] = fmaf(p, a3.w, ascd[15]);
            const float4* vp = (const float4*)(vpg + jrow * 24);
            float4 b0 = vp[0], b1 = vp[1], b2 = vp[2], b3 = vp[3], b4 = vp[4], b5 = vp[5];
            aptd[0]  = fmaf(p, b0.x, aptd[0]);  aptd[1]  = fmaf(p, b0.y, aptd[1]);
            aptd[2]  = fmaf(p, b0.z, aptd[2]);  aptd[3]  = fmaf(p, b0.w, aptd[3]);
            aptd[4]  = fmaf(p, b1.x, aptd[4]);  aptd[5]  = fmaf(p, b1.y, aptd[5]);
            aptd[6]  = fmaf(p, b1.z, aptd[6]);  aptd[7]  = fmaf(p, b1.w, aptd[7]);
            aptd[8]  = fmaf(p, b2.x, aptd[8]);  aptd[9]  = fmaf(p, b2.y, aptd[9]);
            aptd[10] = fmaf(p, b2.z, aptd[10]); aptd[11] = fmaf(p, b2.w, aptd[11]);
            aptd[12] = fmaf(p, b3.x, aptd[12]); aptd[13] = fmaf(p, b3.y, aptd[13]);
            aptd[14] = fmaf(p, b3.z, aptd[14]); aptd[15] = fmaf(p, b3.w, aptd[15]);
            aptd[16] = fmaf(p, b4.x, aptd[16]); aptd[17] = fmaf(p, b4.y, aptd[17]);
            aptd[18] = fmaf(p, b4.z, aptd[18]); aptd[19] = fmaf(p, b4.w, aptd[19]);
            aptd[20] = fmaf(p, b5.x, aptd[20]); aptd[21] = fmaf(p, b5.y, aptd[21]);
            aptd[22] = fmaf(p, b5.z, aptd[22]); aptd[23] = fmaf(p, b5.w, aptd[23]);
        }
        // ---- pair accumulation: lane owns output dim d = l (bank (j+l)%32, free) ----
#pragma unroll
        for (int u = 0; u < JC / 4; ++u) {
            float4 p4 = *(const float4*)&plds[h][4 * u];
            ap = fmaf(p4.x, pw[4 * u + 0][l], ap);
            ap = fmaf(p4.y, pw[4 * u + 1][l], ap);
            ap = fmaf(p4.z, pw[4 * u + 2][l], ap);
            ap = fmaf(p4.w, pw[4 * u + 3][l], ap);
        }
    }

    // ---- epilogue: butterfly-reduce j-partials across 64 lanes ----
#pragma unroll
    for (int off = 32; off > 0; off >>= 1) {
#pragma unroll
        for (int d = 0; d < 16; ++d) ascd[d] += __shfl_xor(ascd[d], off);
#pragma unroll
        for (int d = 0; d < 24; ++d) aptd[d] += __shfl_xor(aptd[d], off);
    }
    const float inv_l = 1.f / lsum;
    float* fb = feats + (size_t)bi * 896;
    if (l < 16) fb[h * 16 + l] = ascd[l] * inv_l;             // m_scalar
    fb[384 + h * 64 + l] = ap * inv_l;                        // m_pair (lane owns d=l)
    const float tr0 = trans[bi * 3 + 0], tr1 = trans[bi * 3 + 1], tr2 = trans[bi * 3 + 2];
    if (l < 24) {
        const int pp = l / 3, r = l - pp * 3;
        const float c0 = aptd[pp * 3 + 0] * inv_l - tr0;
        const float c1 = aptd[pp * 3 + 1] * inv_l - tr1;
        const float c2 = aptd[pp * 3 + 2] * inv_l - tr2;
        const float* Rm = rot + (size_t)bi * 9 + r * 3;       // R[r][c]
        fb[128 + h * 24 + pp * 3 + r] = fmaf(c0, Rm[0], fmaf(c1, Rm[1], c2 * Rm[2]));
    }
    if (l < 8) {
        const float c0 = aptd[l * 3 + 0] * inv_l - tr0;
        const float c1 = aptd[l * 3 + 1] * inv_l - tr1;
        const float c2 = aptd[l * 3 + 2] * inv_l - tr2;
        fb[320 + h * 8 + l] = sqrtf(fmaf(c0, c0, fmaf(c1, c1, fmaf(c2, c2, EPSV))));
    }
}

// ---------------- output projection: 4 tokens/block, 512 blocks (2 blocks/CU) ----------------
__global__ __launch_bounds__(256) void k_out(
    const float* __restrict__ feats, const float* __restrict__ Wout,
    const float* __restrict__ bout, float* __restrict__ out)
{
    __shared__ float fl[4][896];
    const int t = threadIdx.x;
    const int tok0 = blockIdx.x * 4;
    {
        const float4* src = (const float4*)(feats + (size_t)tok0 * 896);
        float4* dst = (float4*)&fl[0][0];
        dst[t] = src[t];
        dst[t + 256] = src[t + 256];
        dst[t + 512] = src[t + 512];
        if (t < 128) dst[t + 768] = src[t + 768];   // 896 float4 total
    }
    __syncthreads();
    const int tok = t >> 6, l = t & 63;
    float2 acc[3];
#pragma unroll
    for (int m = 0; m < 3; ++m) acc[m] = make_float2(0.f, 0.f);
    for (int dd = 0; dd < 896; ++dd) {
        float fv = fl[tok][dd];
        const float* wr = Wout + (size_t)dd * 384;
#pragma unroll
        for (int m = 0; m < 3; ++m) {
            float2 wv = *(const float2*)(wr + 2 * (l + 64 * m));
            acc[m].x = fmaf(fv, wv.x, acc[m].x);
            acc[m].y = fmaf(fv, wv.y, acc[m].y);
        }
    }
    float* ob = out + (size_t)(tok0 + tok) * 384;
#pragma unroll
    for (int m = 0; m < 3; ++m) {
        int c = 2 * (l + 64 * m);
        float2 bv = *(const float2*)(bout + c);
        float2 r = make_float2(acc[m].x + bv.x, acc[m].y + bv.y);
        *(float2*)(ob + c) = r;
    }
}

extern "C" void kernel_launch(void* const* d_in, const int* in_sizes, int n_in,
                              void* d_out, int out_size, void* d_ws, size_t ws_size,
                              hipStream_t stream) {
    const float* x        = (const float*)d_in[0];
    const float* pairw    = (const float*)d_in[1];
    const float* rot      = (const float*)d_in[2];
    const float* trans    = (const float*)d_in[3];
    const int*   pos      = (const int*)d_in[4];
    const float* Wq_s     = (const float*)d_in[6];
    const float* Wk_s     = (const float*)d_in[7];
    const float* Wv_s     = (const float*)d_in[8];
    const float* Wq_p     = (const float*)d_in[9];
    const float* Wk_p     = (const float*)d_in[10];
    const float* Wv_p     = (const float*)d_in[11];
    const float* pweights = (const float*)d_in[12];
    const float* Wpair    = (const float*)d_in[13];
    const float* bpair    = (const float*)d_in[14];
    const float* Wout     = (const float*)d_in[15];
    const float* bout     = (const float*)d_in[16];
    float* out = (float*)d_out;

    float* ws = (float*)d_ws;
    float* cos_t = ws;  ws += 4096;
    float* sin_t = ws;  ws += 4096;
    float* qsg = ws;    ws += BB * HH * NN * DKK;
    float* ksg = ws;    ws += BB * HH * NN * DKK;
    float* vsg = ws;    ws += BB * HH * NN * DVV;
    float* qpg = ws;    ws += BB * HH * NN * 12;
    float* kpg = ws;    ws += BB * HH * NN * 12;
    float* vpg = ws;    ws += BB * HH * NN * 24;
    float* qqg = ws;    ws += BB * HH * NN;
    float* kkg = ws;    ws += BB * HH * NN;
    float* feats = ws;  ws += BB * NN * 896;

    k_rope<<<2, 256, 0, stream>>>(cos_t, sin_t);
    k_proj<<<(BB * NN) / 8, 256, 0, stream>>>(x, rot, trans, pos,
        Wq_s, Wk_s, Wv_s, Wq_p, Wk_p, Wv_p, cos_t, sin_t,
        qsg, ksg, vsg, qpg, kpg, vpg, qqg, kkg);
    k_attn<<<BB * NN, 512, 0, stream>>>(pairw, rot, trans, Wpair, bpair, pweights,
        qsg, ksg, vsg, qpg, kpg, vpg, qqg, kkg, feats);
    k_out<<<(BB * NN) / 4, 256, 0, stream>>>(feats, Wout, bout, out);

    (void)in_sizes; (void)n_in; (void)out_size; (void)ws_size;
}

// Round 5
// 406.996 us; speedup vs baseline: 5.3616x; 1.5331x over previous
//
#include <hip/hip_runtime.h>
#include <math.h>

#define BB 4
#define NN 512
#define DIMX 384
#define HH 8
#define PDD 64
#define JC 64

static constexpr float EPSV = 1e-8f;
static constexpr float SCALAR_SCALE = 0.14433756729740643f;  // (3*16)^-0.5
static constexpr float POINT_SCALE  = 0.1360827634879543f;   // (3*4*4.5)^-0.5
static constexpr float PAIR_SCALE   = 0.5773502691896258f;   // 3^-0.5

// ---------------- rope table ----------------
__global__ void k_rope(float* __restrict__ cos_t, float* __restrict__ sin_t) {
    int n = blockIdx.x * blockDim.x + threadIdx.x;
    if (n >= NN) return;
#pragma unroll
    for (int i = 0; i < 8; ++i) {
        float invf = powf(10000.0f, -(float)i / 8.0f);
        float f = (float)n * invf;
        cos_t[n * 8 + i] = cosf(f);
        sin_t[n * 8 + i] = sinf(f);
    }
}

// ---------------- projections + transforms (column-half split) ----------------
// half 0: qs/ks/vs (cols 0..383) + rope epilogue; half 1: qp/kp/vp (cols 384..767) + rotation epilogue.
// K/V written TRANSPOSED (d-major [bh][d][N]) so k_attn reads are stride-1 coalesced.
__global__ __launch_bounds__(256) void k_proj(
    const float* __restrict__ x, const float* __restrict__ rot,
    const float* __restrict__ trans, const int* __restrict__ pos_ids,
    const float* __restrict__ Wq_s, const float* __restrict__ Wk_s, const float* __restrict__ Wv_s,
    const float* __restrict__ Wq_p, const float* __restrict__ Wk_p, const float* __restrict__ Wv_p,
    const float* __restrict__ cos_t, const float* __restrict__ sin_t,
    float* __restrict__ qsg, float* __restrict__ qpg, float* __restrict__ qqg,
    float4* __restrict__ kst, float* __restrict__ kpt, float* __restrict__ kkg,
    float4* __restrict__ vst, float* __restrict__ vpt)
{
    __shared__ float xl[8][DIMX];
    __shared__ float raw[8][384];
    const int t = threadIdx.x;
    const int tile = blockIdx.x >> 1;
    const int half = blockIdx.x & 1;
    const int tok0 = tile * 8;

    {
        const float4* xg = (const float4*)(x + (size_t)tok0 * DIMX);
        float4* xl4 = (float4*)&xl[0][0];
#pragma unroll
        for (int k = 0; k < 3; ++k) xl4[t + 256 * k] = xg[t + 256 * k];
    }
    __syncthreads();

    const int tok = t >> 5, l = t & 31;
    {
        float4 acc[3];
        const float* wb[3];
        int st[3];
#pragma unroll
        for (int m = 0; m < 3; ++m) {
            int f = l + 32 * m + 96 * half;
            const float* w; int out, c;
            if (f < 32)       { w = Wq_s; out = 128; c = 4 * f; }
            else if (f < 64)  { w = Wk_s; out = 128; c = 4 * f - 128; }
            else if (f < 96)  { w = Wv_s; out = 128; c = 4 * f - 256; }
            else if (f < 120) { w = Wq_p; out = 96;  c = 4 * f - 384; }
            else if (f < 144) { w = Wk_p; out = 96;  c = 4 * f - 480; }
            else              { w = Wv_p; out = 192; c = 4 * f - 576; }
            wb[m] = w + c; st[m] = out;
            acc[m] = make_float4(0.f, 0.f, 0.f, 0.f);
        }
        for (int dd = 0; dd < DIMX; ++dd) {
            float xv = xl[tok][dd];
#pragma unroll
            for (int m = 0; m < 3; ++m) {
                float4 wv = *(const float4*)(wb[m] + (size_t)dd * st[m]);
                acc[m].x = fmaf(xv, wv.x, acc[m].x);
                acc[m].y = fmaf(xv, wv.y, acc[m].y);
                acc[m].z = fmaf(xv, wv.z, acc[m].z);
                acc[m].w = fmaf(xv, wv.w, acc[m].w);
            }
        }
#pragma unroll
        for (int m = 0; m < 3; ++m)
            *(float4*)&raw[tok][4 * (l + 32 * m)] = acc[m];
    }
    __syncthreads();

    const int h = l >> 2, q = l & 3;
    const int n_g = tok0 + tok;
    const int b = n_g / NN;
    const int nloc = n_g - b * NN;
    const int bh = b * HH + h;
    const size_t rowi = (size_t)bh * NN + nloc;

    if (half == 0) {
        const int pos = pos_ids[n_g];
        float qv[4], kv[4], vv[4];
#pragma unroll
        for (int dd0 = 0; dd0 < 4; ++dd0) {
            int dd = q * 4 + dd0;
            int i8 = dd & 7;
            float c = cos_t[pos * 8 + i8], s = sin_t[pos * 8 + i8];
            float xq = raw[tok][h * 16 + dd];
            float rq = (dd < 8) ? -raw[tok][h * 16 + dd + 8] : raw[tok][h * 16 + dd - 8];
            qv[dd0] = fmaf(xq, c, rq * s);
            float xk = raw[tok][128 + h * 16 + dd];
            float rk = (dd < 8) ? -raw[tok][128 + h * 16 + dd + 8] : raw[tok][128 + h * 16 + dd - 8];
            kv[dd0] = fmaf(xk, c, rk * s);
            vv[dd0] = raw[tok][256 + h * 16 + dd];
        }
        *(float4*)&qsg[rowi * 16 + q * 4] = make_float4(qv[0], qv[1], qv[2], qv[3]);
        kst[(size_t)bh * 2048 + q * 512 + nloc] = make_float4(kv[0], kv[1], kv[2], kv[3]);
        vst[(size_t)bh * 2048 + q * 512 + nloc] = make_float4(vv[0], vv[1], vv[2], vv[3]);
    } else {
        const float* Rm = rot + (size_t)n_g * 9;
        const float trv[3] = {trans[n_g * 3 + 0], trans[n_g * 3 + 1], trans[n_g * 3 + 2]};
        float qqp = 0.f, kkp = 0.f;
        {
            float pc[3], kc[3];
#pragma unroll
            for (int c = 0; c < 3; ++c) {
                pc[c] = raw[tok][h * 12 + q * 3 + c];
                kc[c] = raw[tok][96 + h * 12 + q * 3 + c];
            }
#pragma unroll
            for (int r = 0; r < 3; ++r) {
                float vq = trv[r], vk = trv[r];
#pragma unroll
                for (int c = 0; c < 3; ++c) {
                    vq = fmaf(pc[c], Rm[c * 3 + r], vq);
                    vk = fmaf(kc[c], Rm[c * 3 + r], vk);
                }
                qpg[rowi * 12 + q * 3 + r] = vq;
                kpt[(size_t)bh * 6144 + (q * 3 + r) * 512 + nloc] = vk;
                qqp = fmaf(vq, vq, qqp);
                kkp = fmaf(vk, vk, kkp);
            }
        }
        qqp += __shfl_xor(qqp, 1); qqp += __shfl_xor(qqp, 2);
        kkp += __shfl_xor(kkp, 1); kkp += __shfl_xor(kkp, 2);
        if (q == 0) { qqg[rowi] = qqp; kkg[rowi] = kkp; }
#pragma unroll
        for (int pp = 0; pp < 2; ++pp) {
            int p = q + 4 * pp;
            float pc[3];
#pragma unroll
            for (int c = 0; c < 3; ++c) pc[c] = raw[tok][192 + h * 24 + p * 3 + c];
#pragma unroll
            for (int r = 0; r < 3; ++r) {
                float v = trv[r];
#pragma unroll
                for (int c = 0; c < 3; ++c) v = fmaf(pc[c], Rm[c * 3 + r], v);
                vpt[(size_t)bh * 12288 + (p * 3 + r) * 512 + nloc] = v;
            }
        }
    }
}

// ---------------- fused attention: 512 threads, wave = head, lane = j ----------------
// (512,2): min 2 waves/EU -> VGPR cap 256, avoid the 64-VGPR squeeze of rounds 2-4.
__global__ __launch_bounds__(512, 2) void k_attn(
    const float* __restrict__ pairw,
    const float* __restrict__ rot, const float* __restrict__ trans,
    const float* __restrict__ Wpair, const float* __restrict__ bpair,
    const float* __restrict__ pweights,
    const float* __restrict__ qsg, const float* __restrict__ qpg, const float* __restrict__ qqg,
    const float4* __restrict__ kst, const float* __restrict__ kpt, const float* __restrict__ kkg,
    const float4* __restrict__ vst, const float* __restrict__ vpt,
    float* __restrict__ feats)
{
    __shared__ float pw[2][JC][65];    // double-buffered pairwise tile (+1 pad)
    __shared__ float Wp_t[HH][64];     // W_pair transposed [h][d]
    __shared__ float plds[HH][JC];     // per-head probs (same-wave write->read)
    __shared__ float qsh[HH][16];
    __shared__ float qph[HH][12];
    __shared__ float qqh[HH];

    const int t = threadIdx.x;
    const int bi = blockIdx.x;
    const int b = bi >> 9;
    const int h = t >> 6, l = t & 63;  // wave = head, lane = j-in-chunk

    { int d = t >> 3, hh = t & 7; Wp_t[hh][d] = Wpair[t]; }

    const int bh = b * HH + h;
    const size_t rowq = (size_t)bh * NN + (bi & 511);
    if (l < 16) qsh[h][l] = qsg[rowq * 16 + l];
    if (l < 12) qph[h][l] = qpg[rowq * 12 + l];
    if (l == 0) qqh[h] = qqg[rowq];

    const float coefP = -0.5f * log1pf(__expf(pweights[h])) * POINT_SCALE;
    const float bp_h = bpair[h];

    const float4* ksb = kst + (size_t)bh * 2048;   // [4][512] float4
    const float4* vsb = vst + (size_t)bh * 2048;
    const float*  kpb = kpt + (size_t)bh * 6144;   // [12][512]
    const float*  vpb = vpt + (size_t)bh * 12288;  // [24][512]
    const float*  kkb = kkg + (size_t)bh * 512;

    const float4* pwsrc = (const float4*)(pairw + (size_t)bi * NN * PDD);

    // prologue: stage chunk 0 into pw[0]
    {
        float4 vA = pwsrc[t], vB = pwsrc[t + 512];
        int jA = t >> 4, dA = (t & 15) * 4;
        pw[0][jA][dA] = vA.x; pw[0][jA][dA + 1] = vA.y; pw[0][jA][dA + 2] = vA.z; pw[0][jA][dA + 3] = vA.w;
        int f2 = t + 512, jB = f2 >> 4, dB = (f2 & 15) * 4;
        pw[0][jB][dB] = vB.x; pw[0][jB][dB + 1] = vB.y; pw[0][jB][dB + 2] = vB.z; pw[0][jB][dB + 3] = vB.w;
    }
    __syncthreads();

    float m = -3.0e38f, lsum = 0.f, ap = 0.f;
    float ascd[16], aptd[24];
#pragma unroll
    for (int d = 0; d < 16; ++d) ascd[d] = 0.f;
#pragma unroll
    for (int d = 0; d < 24; ++d) aptd[d] = 0.f;

    for (int c = 0; c < NN / JC; ++c) {
        const int cur = c & 1, nxt = cur ^ 1;
        float4 nA, nB;
        const bool more = (c < NN / JC - 1);
        if (more) {
            const float4* s = pwsrc + (size_t)(c + 1) * 1024;
            nA = s[t]; nB = s[t + 512];
        }
        // ---- pair bias for my j (wave-local, 2-way banks = free) ----
        float bias = 0.f;
#pragma unroll
        for (int d = 0; d < 64; ++d)
            bias = fmaf(pw[cur][l][d], Wp_t[h][d], bias);
        bias = (bias + bp_h) * PAIR_SCALE;
        // ---- logit (all loads stride-1 coalesced thanks to d-major K) ----
        const int j = c * JC + l;
        float lg;
        {
            const float4 qs0 = *(const float4*)&qsh[h][0];
            const float4 qs1 = *(const float4*)&qsh[h][4];
            const float4 qs2 = *(const float4*)&qsh[h][8];
            const float4 qs3 = *(const float4*)&qsh[h][12];
            float4 k0 = ksb[j], k1 = ksb[NN + j], k2 = ksb[2 * NN + j], k3 = ksb[3 * NN + j];
            float dot = 0.f;
            dot = fmaf(qs0.x, k0.x, dot); dot = fmaf(qs0.y, k0.y, dot);
            dot = fmaf(qs0.z, k0.z, dot); dot = fmaf(qs0.w, k0.w, dot);
            dot = fmaf(qs1.x, k1.x, dot); dot = fmaf(qs1.y, k1.y, dot);
            dot = fmaf(qs1.z, k1.z, dot); dot = fmaf(qs1.w, k1.w, dot);
            dot = fmaf(qs2.x, k2.x, dot); dot = fmaf(qs2.y, k2.y, dot);
            dot = fmaf(qs2.z, k2.z, dot); dot = fmaf(qs2.w, k2.w, dot);
            dot = fmaf(qs3.x, k3.x, dot); dot = fmaf(qs3.y, k3.y, dot);
            dot = fmaf(qs3.z, k3.z, dot); dot = fmaf(qs3.w, k3.w, dot);
            const float4 qp0 = *(const float4*)&qph[h][0];
            const float4 qp1 = *(const float4*)&qph[h][4];
            const float4 qp2 = *(const float4*)&qph[h][8];
            const float* kpj = kpb + j;
            float pdot = 0.f;
            pdot = fmaf(qp0.x, kpj[0 * NN], pdot);  pdot = fmaf(qp0.y, kpj[1 * NN], pdot);
            pdot = fmaf(qp0.z, kpj[2 * NN], pdot);  pdot = fmaf(qp0.w, kpj[3 * NN], pdot);
            pdot = fmaf(qp1.x, kpj[4 * NN], pdot);  pdot = fmaf(qp1.y, kpj[5 * NN], pdot);
            pdot = fmaf(qp1.z, kpj[6 * NN], pdot);  pdot = fmaf(qp1.w, kpj[7 * NN], pdot);
            pdot = fmaf(qp2.x, kpj[8 * NN], pdot);  pdot = fmaf(qp2.y, kpj[9 * NN], pdot);
            pdot = fmaf(qp2.z, kpj[10 * NN], pdot); pdot = fmaf(qp2.w, kpj[11 * NN], pdot);
            float dist = qqh[h] + kkb[j] - 2.f * pdot;
            lg = fmaf(dot, SCALAR_SCALE, fmaf(coefP, dist, bias));
        }
        // ---- online softmax across the 64-lane wave, defer-rescale (T13) ----
        float cmax = lg;
#pragma unroll
        for (int off = 32; off > 0; off >>= 1) cmax = fmaxf(cmax, __shfl_xor(cmax, off));
        if (cmax > m + 6.f) {          // wave-uniform branch
            const float sc = __expf(m - cmax);
            m = cmax; lsum *= sc; ap *= sc;
#pragma unroll
            for (int d = 0; d < 16; ++d) ascd[d] *= sc;
#pragma unroll
            for (int d = 0; d < 24; ++d) aptd[d] *= sc;
        }
        const float p = __expf(lg - m);
        float psum = p;
#pragma unroll
        for (int off = 32; off > 0; off >>= 1) psum += __shfl_xor(psum, off);
        lsum += psum;
        plds[h][l] = p;
        // ---- v accumulation (coalesced d-major rows) ----
        {
            float4 v0 = vsb[j], v1 = vsb[NN + j], v2 = vsb[2 * NN + j], v3 = vsb[3 * NN + j];
            ascd[0]  = fmaf(p, v0.x, ascd[0]);  ascd[1]  = fmaf(p, v0.y, ascd[1]);
            ascd[2]  = fmaf(p, v0.z, ascd[2]);  ascd[3]  = fmaf(p, v0.w, ascd[3]);
            ascd[4]  = fmaf(p, v1.x, ascd[4]);  ascd[5]  = fmaf(p, v1.y, ascd[5]);
            ascd[6]  = fmaf(p, v1.z, ascd[6]);  ascd[7]  = fmaf(p, v1.w, ascd[7]);
            ascd[8]  = fmaf(p, v2.x, ascd[8]);  ascd[9]  = fmaf(p, v2.y, ascd[9]);
            ascd[10] = fmaf(p, v2.z, ascd[10]); ascd[11] = fmaf(p, v2.w, ascd[11]);
            ascd[12] = fmaf(p, v3.x, ascd[12]); ascd[13] = fmaf(p, v3.y, ascd[13]);
            ascd[14] = fmaf(p, v3.z, ascd[14]); ascd[15] = fmaf(p, v3.w, ascd[15]);
            const float* vpj = vpb + j;
#pragma unroll
            for (int pr = 0; pr < 24; ++pr)
                aptd[pr] = fmaf(p, vpj[pr * NN], aptd[pr]);
        }
        // ---- pair accumulation: lane owns output dim d = l ----
#pragma unroll
        for (int u = 0; u < JC / 4; ++u) {
            float4 p4 = *(const float4*)&plds[h][4 * u];
            ap = fmaf(p4.x, pw[cur][4 * u + 0][l], ap);
            ap = fmaf(p4.y, pw[cur][4 * u + 1][l], ap);
            ap = fmaf(p4.z, pw[cur][4 * u + 2][l], ap);
            ap = fmaf(p4.w, pw[cur][4 * u + 3][l], ap);
        }
        // ---- write next chunk to other buffer ----
        if (more) {
            int jA = t >> 4, dA = (t & 15) * 4;
            pw[nxt][jA][dA] = nA.x; pw[nxt][jA][dA + 1] = nA.y; pw[nxt][jA][dA + 2] = nA.z; pw[nxt][jA][dA + 3] = nA.w;
            int f2 = t + 512, jB = f2 >> 4, dB = (f2 & 15) * 4;
            pw[nxt][jB][dB] = nB.x; pw[nxt][jB][dB + 1] = nB.y; pw[nxt][jB][dB + 2] = nB.z; pw[nxt][jB][dB + 3] = nB.w;
        }
        __syncthreads();
    }

    // ---- epilogue: butterfly-reduce j-partials across 64 lanes ----
#pragma unroll
    for (int off = 32; off > 0; off >>= 1) {
#pragma unroll
        for (int d = 0; d < 16; ++d) ascd[d] += __shfl_xor(ascd[d], off);
#pragma unroll
        for (int d = 0; d < 24; ++d) aptd[d] += __shfl_xor(aptd[d], off);
    }
    const float inv_l = 1.f / lsum;
    float* fb = feats + (size_t)bi * 896;
    if (l < 16) fb[h * 16 + l] = ascd[l] * inv_l;             // m_scalar
    fb[384 + h * 64 + l] = ap * inv_l;                        // m_pair (lane owns d=l)
    const float tr0 = trans[bi * 3 + 0], tr1 = trans[bi * 3 + 1], tr2 = trans[bi * 3 + 2];
    if (l < 24) {
        const int pp = l / 3, r = l - pp * 3;
        const float c0 = aptd[pp * 3 + 0] * inv_l - tr0;
        const float c1 = aptd[pp * 3 + 1] * inv_l - tr1;
        const float c2 = aptd[pp * 3 + 2] * inv_l - tr2;
        const float* Rm = rot + (size_t)bi * 9 + r * 3;       // R[r][c]
        fb[128 + h * 24 + pp * 3 + r] = fmaf(c0, Rm[0], fmaf(c1, Rm[1], c2 * Rm[2]));
    }
    if (l < 8) {
        const float c0 = aptd[l * 3 + 0] * inv_l - tr0;
        const float c1 = aptd[l * 3 + 1] * inv_l - tr1;
        const float c2 = aptd[l * 3 + 2] * inv_l - tr2;
        fb[320 + h * 8 + l] = sqrtf(fmaf(c0, c0, fmaf(c1, c1, fmaf(c2, c2, EPSV))));
    }
}

// ---------------- output projection: 4 tokens x 192-col half per block, 1024 blocks ----------------
__global__ __launch_bounds__(256) void k_out(
    const float* __restrict__ feats, const float* __restrict__ Wout,
    const float* __restrict__ bout, float* __restrict__ out)
{
    __shared__ float fl[4][896];
    const int t = threadIdx.x;
    const int tile = blockIdx.x >> 1;
    const int half = blockIdx.x & 1;
    const int tok0 = tile * 4;
    {
        const float4* src = (const float4*)(feats + (size_t)tok0 * 896);
        float4* dst = (float4*)&fl[0][0];
        dst[t] = src[t];
        dst[t + 256] = src[t + 256];
        dst[t + 512] = src[t + 512];
        if (t < 128) dst[t + 768] = src[t + 768];   // 896 float4 total
    }
    __syncthreads();
    const int tok = t >> 6, l = t & 63;
    const int c0 = 192 * half;
    float acc0 = 0.f, acc1 = 0.f, acc2 = 0.f;
    for (int dd = 0; dd < 896; ++dd) {
        float fv = fl[tok][dd];
        const float* wr = Wout + (size_t)dd * 384 + c0;
        acc0 = fmaf(fv, wr[l], acc0);
        acc1 = fmaf(fv, wr[l + 64], acc1);
        acc2 = fmaf(fv, wr[l + 128], acc2);
    }
    float* ob = out + (size_t)(tok0 + tok) * 384 + c0;
    ob[l]       = acc0 + bout[c0 + l];
    ob[l + 64]  = acc1 + bout[c0 + l + 64];
    ob[l + 128] = acc2 + bout[c0 + l + 128];
}

extern "C" void kernel_launch(void* const* d_in, const int* in_sizes, int n_in,
                              void* d_out, int out_size, void* d_ws, size_t ws_size,
                              hipStream_t stream) {
    const float* x        = (const float*)d_in[0];
    const float* pairw    = (const float*)d_in[1];
    const float* rot      = (const float*)d_in[2];
    const float* trans    = (const float*)d_in[3];
    const int*   pos      = (const int*)d_in[4];
    const float* Wq_s     = (const float*)d_in[6];
    const float* Wk_s     = (const float*)d_in[7];
    const float* Wv_s     = (const float*)d_in[8];
    const float* Wq_p     = (const float*)d_in[9];
    const float* Wk_p     = (const float*)d_in[10];
    const float* Wv_p     = (const float*)d_in[11];
    const float* pweights = (const float*)d_in[12];
    const float* Wpair    = (const float*)d_in[13];
    const float* bpair    = (const float*)d_in[14];
    const float* Wout     = (const float*)d_in[15];
    const float* bout     = (const float*)d_in[16];
    float* out = (float*)d_out;

    float* ws = (float*)d_ws;
    float* cos_t = ws;   ws += 4096;
    float* sin_t = ws;   ws += 4096;
    float* qsg = ws;     ws += BB * HH * NN * 16;    // 262144
    float* qpg = ws;     ws += BB * HH * NN * 12;    // 196608
    float* qqg = ws;     ws += BB * HH * NN;         // 16384
    float4* kst = (float4*)ws; ws += BB * HH * NN * 16;  // [bh][4][N] float4
    float* kpt = ws;     ws += BB * HH * NN * 12;    // [bh][12][N]
    float* kkg = ws;     ws += BB * HH * NN;
    float4* vst = (float4*)ws; ws += BB * HH * NN * 16;
    float* vpt = ws;     ws += BB * HH * NN * 24;    // [bh][24][N]
    float* feats = ws;   ws += BB * NN * 896;

    k_rope<<<2, 256, 0, stream>>>(cos_t, sin_t);
    k_proj<<<(BB * NN) / 8 * 2, 256, 0, stream>>>(x, rot, trans, pos,
        Wq_s, Wk_s, Wv_s, Wq_p, Wk_p, Wv_p, cos_t, sin_t,
        qsg, qpg, qqg, kst, kpt, kkg, vst, vpt);
    k_attn<<<BB * NN, 512, 0, stream>>>(pairw, rot, trans, Wpair, bpair, pweights,
        qsg, qpg, qqg, kst, kpt, kkg, vst, vpt, feats);
    k_out<<<(BB * NN) / 4 * 2, 256, 0, stream>>>(feats, Wout, bout, out);

    (void)in_sizes; (void)n_in; (void)out_size; (void)ws_size;
}